// Round 1
// baseline (9712.329 us; speedup 1.0000x reference)
//
#include <hip/hip_runtime.h>
#include <hip/hip_bf16.h>

#define WAVE 64

__device__ __forceinline__ float wsum(float v) {
#pragma unroll
  for (int m = 32; m > 0; m >>= 1) v += __shfl_xor(v, m, 64);
  return v;
}
__device__ __forceinline__ float wmax(float v) {
#pragma unroll
  for (int m = 32; m > 0; m >>= 1) v = fmaxf(v, __shfl_xor(v, m, 64));
  return v;
}
__device__ __forceinline__ float lrelu(float x) { return x > 0.f ? x : 0.2f * x; }
__device__ __forceinline__ float sigmoidf_(float x) { return 1.f / (1.f + expf(-x)); }

// ---------------- CSR build ----------------
__global__ void hist_k(const int* __restrict__ dst, int* __restrict__ cnt, int e) {
  int i = blockIdx.x * blockDim.x + threadIdx.x;
  if (i < e) atomicAdd(&cnt[dst[i]], 1);
}

__global__ void scan_excl_k(const int* __restrict__ cnt, int* __restrict__ rp, int n) {
  __shared__ int buf[1024];
  __shared__ int carry;
  int tid = threadIdx.x;
  if (tid == 0) carry = 0;
  __syncthreads();
  for (int base = 0; base < n; base += 1024) {
    int i = base + tid;
    int v = (i < n) ? cnt[i] : 0;
    int val = v;
    buf[tid] = val;
    __syncthreads();
    for (int off = 1; off < 1024; off <<= 1) {
      int t = (tid >= off) ? buf[tid - off] : 0;
      __syncthreads();
      val += t;
      buf[tid] = val;
      __syncthreads();
    }
    int c = carry;
    if (i < n) rp[i] = c + val - v;
    __syncthreads();
    if (tid == 1023) carry = c + val;
    __syncthreads();
  }
  if (tid == 0) rp[n] = carry;
}

__global__ void copy_int_k(const int* __restrict__ a, int* __restrict__ b, int n) {
  int i = blockIdx.x * blockDim.x + threadIdx.x;
  if (i < n) b[i] = a[i];
}

__global__ void scatter_k(const int* __restrict__ src, const int* __restrict__ dst,
                          int* __restrict__ cursor, int* __restrict__ srcs, int e) {
  int i = blockIdx.x * blockDim.x + threadIdx.x;
  if (i < e) {
    int pos = atomicAdd(&cursor[dst[i]], 1);
    srcs[pos] = src[i];
  }
}

// ---------------- dense: h = [xa|xb] @ W ; el = h.al ; er = h.ar ----------------
template <int FA>
__global__ __launch_bounds__(256) void mm_k(
    const float* __restrict__ xa, const float* __restrict__ xb,
    const float* __restrict__ W, const float* __restrict__ al, const float* __restrict__ ar,
    float* __restrict__ h, float* __restrict__ el, float* __restrict__ er, int n) {
  constexpr int FIN = FA + 64;
  __shared__ float Wl[FIN * 64];
  for (int i = threadIdx.x; i < FIN * 64; i += 256) Wl[i] = W[i];
  __syncthreads();
  int lane = threadIdx.x & 63, w = threadIdx.x >> 6;
  float alv = al[lane], arv = ar[lane];
  int gw = blockIdx.x * 4 + w, nw = gridDim.x * 4;
  for (int r0 = gw * 4; r0 < n; r0 += nw * 4) {
    int rb = __builtin_amdgcn_readfirstlane(r0);
    int r1 = rb + 1 < n ? rb + 1 : rb;
    int r2 = rb + 2 < n ? rb + 2 : rb;
    int r3 = rb + 3 < n ? rb + 3 : rb;
    float acc0 = 0.f, acc1 = 0.f, acc2 = 0.f, acc3 = 0.f;
    const float* p0 = xa + (size_t)rb * FA;
    const float* p1 = xa + (size_t)r1 * FA;
    const float* p2 = xa + (size_t)r2 * FA;
    const float* p3 = xa + (size_t)r3 * FA;
#pragma unroll
    for (int k = 0; k < FA; k++) {
      float wv = Wl[k * 64 + lane];
      acc0 += p0[k] * wv; acc1 += p1[k] * wv;
      acc2 += p2[k] * wv; acc3 += p3[k] * wv;
    }
    const float* q0 = xb + (size_t)rb * 64;
    const float* q1 = xb + (size_t)r1 * 64;
    const float* q2 = xb + (size_t)r2 * 64;
    const float* q3 = xb + (size_t)r3 * 64;
#pragma unroll 8
    for (int k = 0; k < 64; k++) {
      float wv = Wl[(FA + k) * 64 + lane];
      acc0 += q0[k] * wv; acc1 += q1[k] * wv;
      acc2 += q2[k] * wv; acc3 += q3[k] * wv;
    }
    h[(size_t)rb * 64 + lane] = acc0;
    if (rb + 1 < n) h[(size_t)(rb + 1) * 64 + lane] = acc1;
    if (rb + 2 < n) h[(size_t)(rb + 2) * 64 + lane] = acc2;
    if (rb + 3 < n) h[(size_t)(rb + 3) * 64 + lane] = acc3;
    float s;
    s = wsum(acc0 * alv); if (lane == 0) el[rb] = s;
    s = wsum(acc0 * arv); if (lane == 0) er[rb] = s;
    if (rb + 1 < n) {
      s = wsum(acc1 * alv); if (lane == 0) el[rb + 1] = s;
      s = wsum(acc1 * arv); if (lane == 0) er[rb + 1] = s;
    }
    if (rb + 2 < n) {
      s = wsum(acc2 * alv); if (lane == 0) el[rb + 2] = s;
      s = wsum(acc2 * arv); if (lane == 0) er[rb + 2] = s;
    }
    if (rb + 3 < n) {
      s = wsum(acc3 * alv); if (lane == 0) el[rb + 3] = s;
      s = wsum(acc3 * arv); if (lane == 0) er[rb + 3] = s;
    }
  }
}

// ---------------- edge softmax + aggregate, gates r,z fused ----------------
__global__ __launch_bounds__(256) void agg_rz_k(
    const int* __restrict__ rp, const int* __restrict__ srcs,
    const float* __restrict__ hr, const float* __restrict__ elr, const float* __restrict__ err_,
    const float* __restrict__ hz, const float* __restrict__ elz, const float* __restrict__ erz,
    const float* __restrict__ br, const float* __restrict__ bz,
    const float* __restrict__ hx, float* __restrict__ rh, float* __restrict__ zb, int n) {
  __shared__ float exr[4][64], exz[4][64];
  __shared__ int sb[4][64];
  int lane = threadIdx.x & 63, w = threadIdx.x >> 6;
  int d = (blockIdx.x * blockDim.x + threadIdx.x) >> 6;
  int stride = (gridDim.x * blockDim.x) >> 6;
  for (; d < n; d += stride) {
    int beg = rp[d], end = rp[d + 1];
    int deg = end - beg;
    float accr = 0.f, accz = 0.f;
    if (deg > 0) {
      float erd_r = err_[d], erd_z = erz[d];
      if (deg <= 64) {
        float e_r = -1e30f, e_z = -1e30f;
        if (lane < deg) {
          int s = srcs[beg + lane];
          sb[w][lane] = s;
          e_r = lrelu(elr[s] + erd_r);
          e_z = lrelu(elz[s] + erd_z);
        }
        float mr = wmax(e_r), mz = wmax(e_z);
        float xr = (lane < deg) ? expf(e_r - mr) : 0.f;
        float xz = (lane < deg) ? expf(e_z - mz) : 0.f;
        float sr = wsum(xr), sz = wsum(xz);
        exr[w][lane] = xr / fmaxf(sr, 1e-9f);
        exz[w][lane] = xz / fmaxf(sz, 1e-9f);
        for (int k = 0; k < deg; k++) {
          int sk = sb[w][k];
          float ar_ = exr[w][k], az_ = exz[w][k];
          accr += ar_ * hr[(size_t)sk * 64 + lane];
          accz += az_ * hz[(size_t)sk * 64 + lane];
        }
      } else {
        float mr = -1e30f, mz = -1e30f;
        for (int k = lane; k < deg; k += 64) {
          int s = srcs[beg + k];
          mr = fmaxf(mr, lrelu(elr[s] + erd_r));
          mz = fmaxf(mz, lrelu(elz[s] + erd_z));
        }
        mr = wmax(mr); mz = wmax(mz);
        float sr = 0.f, sz = 0.f;
        for (int k = lane; k < deg; k += 64) {
          int s = srcs[beg + k];
          sr += expf(lrelu(elr[s] + erd_r) - mr);
          sz += expf(lrelu(elz[s] + erd_z) - mz);
        }
        sr = fmaxf(wsum(sr), 1e-9f);
        sz = fmaxf(wsum(sz), 1e-9f);
        for (int k = 0; k < deg; k++) {
          int s = srcs[beg + k];
          float ar_ = expf(lrelu(elr[s] + erd_r) - mr) / sr;
          float az_ = expf(lrelu(elz[s] + erd_z) - mz) / sz;
          accr += ar_ * hr[(size_t)s * 64 + lane];
          accz += az_ * hz[(size_t)s * 64 + lane];
        }
      }
    }
    float r = sigmoidf_(accr + br[lane]);
    float z = sigmoidf_(accz + bz[lane]);
    float hxv = hx[(size_t)d * 64 + lane];
    rh[(size_t)d * 64 + lane] = r * hxv;
    zb[(size_t)d * 64 + lane] = z;
  }
}

// ---------------- edge softmax + aggregate, candidate gate + state update ----------------
__global__ __launch_bounds__(256) void agg_c_k(
    const int* __restrict__ rp, const int* __restrict__ srcs,
    const float* __restrict__ hc, const float* __restrict__ elc, const float* __restrict__ erc,
    const float* __restrict__ bc, const float* __restrict__ zb, float* __restrict__ hstate, int n) {
  __shared__ float exc[4][64];
  __shared__ int sb[4][64];
  int lane = threadIdx.x & 63, w = threadIdx.x >> 6;
  int d = (blockIdx.x * blockDim.x + threadIdx.x) >> 6;
  int stride = (gridDim.x * blockDim.x) >> 6;
  for (; d < n; d += stride) {
    int beg = rp[d], end = rp[d + 1];
    int deg = end - beg;
    float acc = 0.f;
    if (deg > 0) {
      float erd = erc[d];
      if (deg <= 64) {
        float e_c = -1e30f;
        if (lane < deg) {
          int s = srcs[beg + lane];
          sb[w][lane] = s;
          e_c = lrelu(elc[s] + erd);
        }
        float m = wmax(e_c);
        float xc = (lane < deg) ? expf(e_c - m) : 0.f;
        float ssum = wsum(xc);
        exc[w][lane] = xc / fmaxf(ssum, 1e-9f);
        for (int k = 0; k < deg; k++) {
          int sk = sb[w][k];
          acc += exc[w][k] * hc[(size_t)sk * 64 + lane];
        }
      } else {
        float m = -1e30f;
        for (int k = lane; k < deg; k += 64) {
          int s = srcs[beg + k];
          m = fmaxf(m, lrelu(elc[s] + erd));
        }
        m = wmax(m);
        float ssum = 0.f;
        for (int k = lane; k < deg; k += 64) {
          int s = srcs[beg + k];
          ssum += expf(lrelu(elc[s] + erd) - m);
        }
        ssum = fmaxf(wsum(ssum), 1e-9f);
        for (int k = 0; k < deg; k++) {
          int s = srcs[beg + k];
          float a = expf(lrelu(elc[s] + erd) - m) / ssum;
          acc += a * hc[(size_t)s * 64 + lane];
        }
      }
    }
    float hcv = tanhf(acc + bc[lane]);
    float z = zb[(size_t)d * 64 + lane];
    float hxv = hstate[(size_t)d * 64 + lane];
    hstate[(size_t)d * 64 + lane] = z * hxv + (1.f - z) * hcv;
  }
}

// ---------------- final projection: out = h @ Wp + bp ----------------
__global__ __launch_bounds__(256) void proj_k(
    const float* __restrict__ h, const float* __restrict__ W,
    const float* __restrict__ b, float* __restrict__ out, int n) {
  int lane = threadIdx.x & 63;
  int d = (blockIdx.x * blockDim.x + threadIdx.x) >> 6;
  if (d >= n) return;
  float v = h[(size_t)d * 64 + lane];
  float s0 = wsum(v * W[lane * 2 + 0]);
  float s1 = wsum(v * W[lane * 2 + 1]);
  if (lane == 0) {
    out[(size_t)d * 2 + 0] = s0 + b[0];
    out[(size_t)d * 2 + 1] = s1 + b[1];
  }
}

extern "C" void kernel_launch(void* const* d_in, const int* in_sizes, int n_in,
                              void* d_out, int out_size, void* d_ws, size_t ws_size,
                              hipStream_t stream) {
  const int T = 12, HZN = 12, F = 2, H = 64;
  const float* x = (const float*)d_in[0];
  const int* src = (const int*)d_in[1];
  const int* dst = (const int*)d_in[2];
  const float* enc_W0 = (const float*)d_in[3];
  const float* enc_al0 = (const float*)d_in[4];
  const float* enc_ar0 = (const float*)d_in[5];
  const float* enc_b0 = (const float*)d_in[6];
  const float* enc_W1 = (const float*)d_in[7];
  const float* enc_al1 = (const float*)d_in[8];
  const float* enc_ar1 = (const float*)d_in[9];
  const float* enc_b1 = (const float*)d_in[10];
  const float* dec_W0 = (const float*)d_in[11];
  const float* dec_al0 = (const float*)d_in[12];
  const float* dec_ar0 = (const float*)d_in[13];
  const float* dec_b0 = (const float*)d_in[14];
  const float* dec_W1 = (const float*)d_in[15];
  const float* dec_al1 = (const float*)d_in[16];
  const float* dec_ar1 = (const float*)d_in[17];
  const float* dec_b1 = (const float*)d_in[18];
  const float* proj_W = (const float*)d_in[19];
  const float* proj_b = (const float*)d_in[20];
  float* out = (float*)d_out;

  const int E = in_sizes[1];
  const int N = in_sizes[0] / (T * F);

  // ---- workspace carve ----
  char* wp = (char*)d_ws;
  size_t off = 0;
  auto carve = [&](size_t bytes) {
    void* p = wp + off;
    off = (off + bytes + 255) & ~(size_t)255;
    return p;
  };
  int* counts = (int*)carve((size_t)(N + 1) * 4);
  int* rp = (int*)carve((size_t)(N + 1) * 4);
  int* cursor = (int*)carve((size_t)N * 4);
  int* srcs = (int*)carve((size_t)E * 4);
  float* hs0 = (float*)carve((size_t)N * H * 4);
  float* hs1 = (float*)carve((size_t)N * H * 4);
  float* h_r = (float*)carve((size_t)N * H * 4);
  float* h_z = (float*)carve((size_t)N * H * 4);
  float* rh = (float*)carve((size_t)N * H * 4);
  float* zbuf = (float*)carve((size_t)N * H * 4);
  float* el_r = (float*)carve((size_t)N * 4);
  float* er_r = (float*)carve((size_t)N * 4);
  float* el_z = (float*)carve((size_t)N * 4);
  float* er_z = (float*)carve((size_t)N * 4);
  float* zero2 = (float*)carve((size_t)N * F * 4);
  (void)ws_size;

  const int G_E = (E + 255) / 256;
  const int G_N = (N + 255) / 256;
  const int G_MM = (N + 15) / 16;   // 4 waves * 4 rows per block
  const int G_AG = (N + 3) / 4;     // 1 wave per dst

  // ---- CSR by destination (once per launch) ----
  hipMemsetAsync(counts, 0, (size_t)(N + 1) * 4, stream);
  hist_k<<<G_E, 256, 0, stream>>>(dst, counts, E);
  scan_excl_k<<<1, 1024, 0, stream>>>(counts, rp, N);
  copy_int_k<<<G_N, 256, 0, stream>>>(rp, cursor, N);
  scatter_k<<<G_E, 256, 0, stream>>>(src, dst, cursor, srcs, E);

  // ---- init states ----
  hipMemsetAsync(hs0, 0, (size_t)N * H * 4, stream);
  hipMemsetAsync(hs1, 0, (size_t)N * H * 4, stream);
  hipMemsetAsync(zero2, 0, (size_t)N * F * 4, stream);

  // ---- one GRU cell (graph-conv gated) ----
  auto run_gru = [&](const float* xa, int FA, float* hstate,
                     const float* W, const float* al, const float* ar, const float* b) {
    int fin = FA + H;
    // gate 0 (r), gate 1 (z)
    if (FA == 2) {
      mm_k<2><<<G_MM, 256, 0, stream>>>(xa, hstate, W, al, ar, h_r, el_r, er_r, N);
      mm_k<2><<<G_MM, 256, 0, stream>>>(xa, hstate, W + (size_t)fin * H, al + H, ar + H,
                                        h_z, el_z, er_z, N);
    } else {
      mm_k<64><<<G_MM, 256, 0, stream>>>(xa, hstate, W, al, ar, h_r, el_r, er_r, N);
      mm_k<64><<<G_MM, 256, 0, stream>>>(xa, hstate, W + (size_t)fin * H, al + H, ar + H,
                                         h_z, el_z, er_z, N);
    }
    agg_rz_k<<<G_AG, 256, 0, stream>>>(rp, srcs, h_r, el_r, er_r, h_z, el_z, er_z,
                                       b, b + H, hstate, rh, zbuf, N);
    // gate 2 (candidate), input [xa | r*hx]; reuse h_r/el_r/er_r buffers
    if (FA == 2) {
      mm_k<2><<<G_MM, 256, 0, stream>>>(xa, rh, W + (size_t)2 * fin * H, al + 2 * H, ar + 2 * H,
                                        h_r, el_r, er_r, N);
    } else {
      mm_k<64><<<G_MM, 256, 0, stream>>>(xa, rh, W + (size_t)2 * fin * H, al + 2 * H, ar + 2 * H,
                                         h_r, el_r, er_r, N);
    }
    agg_c_k<<<G_AG, 256, 0, stream>>>(rp, srcs, h_r, el_r, er_r, b + 2 * H, zbuf, hstate, N);
  };

  // ---- encoder ----
  for (int t = 0; t < T; t++) {
    const float* xt = x + (size_t)t * N * F;
    run_gru(xt, 2, hs0, enc_W0, enc_al0, enc_ar0, enc_b0);
    run_gru(hs0, 64, hs1, enc_W1, enc_al1, enc_ar1, enc_b1);
  }

  // ---- decoder ----
  for (int t = 0; t < HZN; t++) {
    const float* xin = (t == 0) ? zero2 : (out + (size_t)(t - 1) * N * 2);
    run_gru(xin, 2, hs0, dec_W0, dec_al0, dec_ar0, dec_b0);
    run_gru(hs0, 64, hs1, dec_W1, dec_al1, dec_ar1, dec_b1);
    proj_k<<<G_AG, 256, 0, stream>>>(hs1, proj_W, proj_b, out + (size_t)t * N * 2, N);
  }
  (void)out_size; (void)n_in;
}

// Round 2
// 8902.797 us; speedup vs baseline: 1.0909x; 1.0909x over previous
//
#include <hip/hip_runtime.h>
#include <hip/hip_bf16.h>

__device__ __forceinline__ float wsum64(float v) {
#pragma unroll
  for (int m = 32; m > 0; m >>= 1) v += __shfl_xor(v, m, 64);
  return v;
}
__device__ __forceinline__ float gsum16(float v) {
#pragma unroll
  for (int m = 8; m > 0; m >>= 1) v += __shfl_xor(v, m, 16);
  return v;
}
__device__ __forceinline__ float lrelu(float x) { return x > 0.f ? x : 0.2f * x; }
__device__ __forceinline__ float sigf(float x) { return 1.f / (1.f + __expf(-x)); }

// ---------------- CSR build ----------------
__global__ void hist_k(const int* __restrict__ dst, int* __restrict__ cnt, int e) {
  int i = blockIdx.x * blockDim.x + threadIdx.x;
  if (i < e) atomicAdd(&cnt[dst[i]], 1);
}

__global__ void scan_excl_k(const int* __restrict__ cnt, int* __restrict__ rp, int n) {
  __shared__ int buf[1024];
  __shared__ int carry;
  int tid = threadIdx.x;
  if (tid == 0) carry = 0;
  __syncthreads();
  for (int base = 0; base < n; base += 1024) {
    int i = base + tid;
    int v = (i < n) ? cnt[i] : 0;
    int val = v;
    buf[tid] = val;
    __syncthreads();
    for (int off = 1; off < 1024; off <<= 1) {
      int t = (tid >= off) ? buf[tid - off] : 0;
      __syncthreads();
      val += t;
      buf[tid] = val;
      __syncthreads();
    }
    int c = carry;
    if (i < n) rp[i] = c + val - v;
    __syncthreads();
    if (tid == 1023) carry = c + val;
    __syncthreads();
  }
  if (tid == 0) rp[n] = carry;
}

__global__ void copy_int_k(const int* __restrict__ a, int* __restrict__ b, int n) {
  int i = blockIdx.x * blockDim.x + threadIdx.x;
  if (i < n) b[i] = a[i];
}

__global__ void scatter_k(const int* __restrict__ src, const int* __restrict__ dst,
                          int* __restrict__ cursor, int* __restrict__ srcs, int e) {
  int i = blockIdx.x * blockDim.x + threadIdx.x;
  if (i < e) {
    int pos = atomicAdd(&cursor[dst[i]], 1);
    srcs[pos] = src[i];
  }
}

// ---------------- fused dense r+z gates ----------------
// h_r,h_z = [xa|xb] @ {Wr,Wz}; el/er logits for both gates, interleaved outputs.
template <int FA>
__global__ __launch_bounds__(512) void mm_rz_k(
    const float* __restrict__ xa, const float* __restrict__ xb,
    const float* __restrict__ Wg,   // gates 0,1 at Wg, Wg+FIN*64
    const float* __restrict__ al,   // [3][64]
    const float* __restrict__ ar,
    float* __restrict__ hbuf,       // [N][2][64] (r row, z row adjacent)
    float* __restrict__ elrz,       // [N][2]
    float* __restrict__ errz,       // [N][2]
    int n) {
  constexpr int FIN = FA + 64;
  __shared__ float Wl[FIN * 128];   // interleaved (wr, wz) per [k][lane]
  const float* Wr = Wg;
  const float* Wz = Wg + FIN * 64;
  for (int i = threadIdx.x; i < FIN * 64; i += 512) {
    Wl[i * 2 + 0] = Wr[i];
    Wl[i * 2 + 1] = Wz[i];
  }
  __syncthreads();
  int lane = threadIdx.x & 63, w = threadIdx.x >> 6;
  float alr = al[lane], arr_ = ar[lane];
  float alz = al[64 + lane], arz = ar[64 + lane];
  int rb = __builtin_amdgcn_readfirstlane(blockIdx.x * 64 + w * 8);
  if (rb >= n) return;
  float accr[8], accz[8];
#pragma unroll
  for (int i = 0; i < 8; i++) { accr[i] = 0.f; accz[i] = 0.f; }
  const float* pa[8];
  const float* pb[8];
#pragma unroll
  for (int i = 0; i < 8; i++) {
    int r = rb + i; if (r >= n) r = n - 1;
    pa[i] = xa + (size_t)r * FA;
    pb[i] = xb + (size_t)r * 64;
  }
#pragma unroll
  for (int k = 0; k < FA; k++) {
    float2 wv = *(const float2*)&Wl[(size_t)(k * 64 + lane) * 2];
#pragma unroll
    for (int i = 0; i < 8; i++) {
      float v = pa[i][k];
      accr[i] = fmaf(v, wv.x, accr[i]);
      accz[i] = fmaf(v, wv.y, accz[i]);
    }
  }
#pragma unroll 4
  for (int k = 0; k < 64; k++) {
    float2 wv = *(const float2*)&Wl[(size_t)((FA + k) * 64 + lane) * 2];
#pragma unroll
    for (int i = 0; i < 8; i++) {
      float v = pb[i][k];
      accr[i] = fmaf(v, wv.x, accr[i]);
      accz[i] = fmaf(v, wv.y, accz[i]);
    }
  }
#pragma unroll
  for (int i = 0; i < 8; i++) {
    int r = rb + i;
    bool ok = r < n;
    if (ok) {
      hbuf[(size_t)r * 128 + lane] = accr[i];
      hbuf[(size_t)r * 128 + 64 + lane] = accz[i];
    }
    float s;
    s = wsum64(accr[i] * alr);  if (ok && lane == 0) elrz[(size_t)r * 2 + 0] = s;
    s = wsum64(accz[i] * alz);  if (ok && lane == 0) elrz[(size_t)r * 2 + 1] = s;
    s = wsum64(accr[i] * arr_); if (ok && lane == 0) errz[(size_t)r * 2 + 0] = s;
    s = wsum64(accz[i] * arz);  if (ok && lane == 0) errz[(size_t)r * 2 + 1] = s;
  }
}

// ---------------- dense candidate gate ----------------
template <int FA>
__global__ __launch_bounds__(512) void mm_c_k(
    const float* __restrict__ xa, const float* __restrict__ xb,
    const float* __restrict__ Wc, const float* __restrict__ al, const float* __restrict__ ar,
    float* __restrict__ hc, float* __restrict__ elc, float* __restrict__ erc, int n) {
  constexpr int FIN = FA + 64;
  __shared__ float Wl[FIN * 64];
  for (int i = threadIdx.x; i < FIN * 64; i += 512) Wl[i] = Wc[i];
  __syncthreads();
  int lane = threadIdx.x & 63, w = threadIdx.x >> 6;
  float alv = al[lane], arv = ar[lane];
  int rb = __builtin_amdgcn_readfirstlane(blockIdx.x * 64 + w * 8);
  if (rb >= n) return;
  float acc[8];
#pragma unroll
  for (int i = 0; i < 8; i++) acc[i] = 0.f;
  const float* pa[8];
  const float* pb[8];
#pragma unroll
  for (int i = 0; i < 8; i++) {
    int r = rb + i; if (r >= n) r = n - 1;
    pa[i] = xa + (size_t)r * FA;
    pb[i] = xb + (size_t)r * 64;
  }
#pragma unroll
  for (int k = 0; k < FA; k++) {
    float wv = Wl[k * 64 + lane];
#pragma unroll
    for (int i = 0; i < 8; i++) acc[i] = fmaf(pa[i][k], wv, acc[i]);
  }
#pragma unroll 4
  for (int k = 0; k < 64; k++) {
    float wv = Wl[(FA + k) * 64 + lane];
#pragma unroll
    for (int i = 0; i < 8; i++) acc[i] = fmaf(pb[i][k], wv, acc[i]);
  }
#pragma unroll
  for (int i = 0; i < 8; i++) {
    int r = rb + i;
    bool ok = r < n;
    if (ok) hc[(size_t)r * 64 + lane] = acc[i];
    float s;
    s = wsum64(acc[i] * alv); if (ok && lane == 0) elc[r] = s;
    s = wsum64(acc[i] * arv); if (ok && lane == 0) erc[r] = s;
  }
}

// ---------------- edge softmax + aggregate r,z (16-lane groups, float4) ----------------
__global__ __launch_bounds__(256) void agg_rz_k(
    const int* __restrict__ rp, const int* __restrict__ srcs,
    const float* __restrict__ hbuf, const float* __restrict__ elrz, const float* __restrict__ errz,
    const float* __restrict__ b,     // gates 0,1 bias at b, b+64
    const float* __restrict__ hx, float* __restrict__ rh, float* __restrict__ zb, int n) {
  int l16 = threadIdx.x & 15;
  int d = (blockIdx.x * 256 + threadIdx.x) >> 4;
  if (d >= n) return;
  int beg = rp[d], deg = rp[d + 1] - beg;
  float2 erd = ((const float2*)errz)[d];
  const float4* h4 = (const float4*)hbuf;
  float4 accr = {0, 0, 0, 0}, accz = {0, 0, 0, 0};
  float sr = 0.f, sz = 0.f;
  for (int base = 0; base < deg; base += 16) {
    int k = base + l16;
    int s = 0; float exr = 0.f, exz = 0.f;
    if (k < deg) {
      s = srcs[beg + k];
      float2 el = ((const float2*)elrz)[s];
      exr = __expf(lrelu(el.x + erd.x));
      exz = __expf(lrelu(el.y + erd.y));
      sr += exr; sz += exz;
    }
    int lim = deg - base; if (lim > 16) lim = 16;
    for (int j = 0; j < lim; j++) {
      int sj = __shfl(s, j, 16);
      float aj = __shfl(exr, j, 16);
      float zj = __shfl(exz, j, 16);
      float4 hr = h4[(size_t)sj * 32 + l16];
      float4 hz = h4[(size_t)sj * 32 + 16 + l16];
      accr.x = fmaf(aj, hr.x, accr.x); accr.y = fmaf(aj, hr.y, accr.y);
      accr.z = fmaf(aj, hr.z, accr.z); accr.w = fmaf(aj, hr.w, accr.w);
      accz.x = fmaf(zj, hz.x, accz.x); accz.y = fmaf(zj, hz.y, accz.y);
      accz.z = fmaf(zj, hz.z, accz.z); accz.w = fmaf(zj, hz.w, accz.w);
    }
  }
  sr = gsum16(sr); sz = gsum16(sz);
  float invr = 1.f / fmaxf(sr, 1e-9f);
  float invz = 1.f / fmaxf(sz, 1e-9f);
  float4 br4 = ((const float4*)b)[l16];
  float4 bz4 = ((const float4*)(b + 64))[l16];
  float4 hx4 = ((const float4*)hx)[(size_t)d * 16 + l16];
  float4 rv, zv;
  rv.x = sigf(fmaf(accr.x, invr, br4.x)) * hx4.x;
  rv.y = sigf(fmaf(accr.y, invr, br4.y)) * hx4.y;
  rv.z = sigf(fmaf(accr.z, invr, br4.z)) * hx4.z;
  rv.w = sigf(fmaf(accr.w, invr, br4.w)) * hx4.w;
  zv.x = sigf(fmaf(accz.x, invz, bz4.x));
  zv.y = sigf(fmaf(accz.y, invz, bz4.y));
  zv.z = sigf(fmaf(accz.z, invz, bz4.z));
  zv.w = sigf(fmaf(accz.w, invz, bz4.w));
  ((float4*)rh)[(size_t)d * 16 + l16] = rv;
  ((float4*)zb)[(size_t)d * 16 + l16] = zv;
}

// ---------------- candidate aggregate + state update (+ optional proj) ----------------
__global__ __launch_bounds__(256) void agg_c_k(
    const int* __restrict__ rp, const int* __restrict__ srcs,
    const float* __restrict__ hc, const float* __restrict__ elc, const float* __restrict__ erc,
    const float* __restrict__ b, const float* __restrict__ zb, float* __restrict__ hstate,
    const float* __restrict__ projW, const float* __restrict__ projb,
    float* __restrict__ outp, int n) {
  int l16 = threadIdx.x & 15;
  int d = (blockIdx.x * 256 + threadIdx.x) >> 4;
  if (d >= n) return;
  int beg = rp[d], deg = rp[d + 1] - beg;
  float erd = erc[d];
  const float4* h4 = (const float4*)hc;
  float4 acc = {0, 0, 0, 0};
  float ssum = 0.f;
  for (int base = 0; base < deg; base += 16) {
    int k = base + l16;
    int s = 0; float ex = 0.f;
    if (k < deg) {
      s = srcs[beg + k];
      ex = __expf(lrelu(elc[s] + erd));
      ssum += ex;
    }
    int lim = deg - base; if (lim > 16) lim = 16;
    for (int j = 0; j < lim; j++) {
      int sj = __shfl(s, j, 16);
      float aj = __shfl(ex, j, 16);
      float4 hv = h4[(size_t)sj * 16 + l16];
      acc.x = fmaf(aj, hv.x, acc.x); acc.y = fmaf(aj, hv.y, acc.y);
      acc.z = fmaf(aj, hv.z, acc.z); acc.w = fmaf(aj, hv.w, acc.w);
    }
  }
  ssum = gsum16(ssum);
  float inv = 1.f / fmaxf(ssum, 1e-9f);
  float4 bc4 = ((const float4*)b)[l16];
  float4 z4 = ((const float4*)zb)[(size_t)d * 16 + l16];
  float4 hx4 = ((const float4*)hstate)[(size_t)d * 16 + l16];
  float4 hcv, hn;
  hcv.x = tanhf(fmaf(acc.x, inv, bc4.x));
  hcv.y = tanhf(fmaf(acc.y, inv, bc4.y));
  hcv.z = tanhf(fmaf(acc.z, inv, bc4.z));
  hcv.w = tanhf(fmaf(acc.w, inv, bc4.w));
  hn.x = z4.x * hx4.x + (1.f - z4.x) * hcv.x;
  hn.y = z4.y * hx4.y + (1.f - z4.y) * hcv.y;
  hn.z = z4.z * hx4.z + (1.f - z4.z) * hcv.z;
  hn.w = z4.w * hx4.w + (1.f - z4.w) * hcv.w;
  ((float4*)hstate)[(size_t)d * 16 + l16] = hn;
  if (outp) {
    const float4* wp4 = (const float4*)projW;   // [64][2] row-major
    float4 a0 = wp4[l16 * 2], a1 = wp4[l16 * 2 + 1];
    float p0 = hn.x * a0.x + hn.y * a0.z + hn.z * a1.x + hn.w * a1.z;
    float p1 = hn.x * a0.y + hn.y * a0.w + hn.z * a1.y + hn.w * a1.w;
    p0 = gsum16(p0); p1 = gsum16(p1);
    if (l16 == 0) {
      outp[(size_t)d * 2 + 0] = p0 + projb[0];
      outp[(size_t)d * 2 + 1] = p1 + projb[1];
    }
  }
}

extern "C" void kernel_launch(void* const* d_in, const int* in_sizes, int n_in,
                              void* d_out, int out_size, void* d_ws, size_t ws_size,
                              hipStream_t stream) {
  const int T = 12, HZN = 12, F = 2, H = 64;
  const float* x = (const float*)d_in[0];
  const int* src = (const int*)d_in[1];
  const int* dst = (const int*)d_in[2];
  const float* enc_W0 = (const float*)d_in[3];
  const float* enc_al0 = (const float*)d_in[4];
  const float* enc_ar0 = (const float*)d_in[5];
  const float* enc_b0 = (const float*)d_in[6];
  const float* enc_W1 = (const float*)d_in[7];
  const float* enc_al1 = (const float*)d_in[8];
  const float* enc_ar1 = (const float*)d_in[9];
  const float* enc_b1 = (const float*)d_in[10];
  const float* dec_W0 = (const float*)d_in[11];
  const float* dec_al0 = (const float*)d_in[12];
  const float* dec_ar0 = (const float*)d_in[13];
  const float* dec_b0 = (const float*)d_in[14];
  const float* dec_W1 = (const float*)d_in[15];
  const float* dec_al1 = (const float*)d_in[16];
  const float* dec_ar1 = (const float*)d_in[17];
  const float* dec_b1 = (const float*)d_in[18];
  const float* proj_W = (const float*)d_in[19];
  const float* proj_b = (const float*)d_in[20];
  float* out = (float*)d_out;

  const int E = in_sizes[1];
  const int N = in_sizes[0] / (T * F);

  char* wp = (char*)d_ws;
  size_t off = 0;
  auto carve = [&](size_t bytes) {
    void* p = wp + off;
    off = (off + bytes + 255) & ~(size_t)255;
    return p;
  };
  int* counts = (int*)carve((size_t)(N + 1) * 4);
  int* rp = (int*)carve((size_t)(N + 1) * 4);
  int* cursor = (int*)carve((size_t)N * 4);
  int* srcs = (int*)carve((size_t)E * 4);
  float* hs0 = (float*)carve((size_t)N * H * 4);
  float* hs1 = (float*)carve((size_t)N * H * 4);
  float* hbuf = (float*)carve((size_t)N * 2 * H * 4);
  float* elrz = (float*)carve((size_t)N * 2 * 4);
  float* errz = (float*)carve((size_t)N * 2 * 4);
  float* hc = (float*)carve((size_t)N * H * 4);
  float* elc = (float*)carve((size_t)N * 4);
  float* erc = (float*)carve((size_t)N * 4);
  float* rh = (float*)carve((size_t)N * H * 4);
  float* zbuf = (float*)carve((size_t)N * H * 4);
  float* zero2 = (float*)carve((size_t)N * F * 4);
  (void)ws_size;

  const int G_E = (E + 255) / 256;
  const int G_N = (N + 255) / 256;
  const int G_MM = (N + 63) / 64;   // 512 thr: 8 waves * 8 rows
  const int G_AG = (N + 15) / 16;   // 256 thr: 16 groups of 16 lanes

  // ---- CSR by destination ----
  hipMemsetAsync(counts, 0, (size_t)(N + 1) * 4, stream);
  hist_k<<<G_E, 256, 0, stream>>>(dst, counts, E);
  scan_excl_k<<<1, 1024, 0, stream>>>(counts, rp, N);
  copy_int_k<<<G_N, 256, 0, stream>>>(rp, cursor, N);
  scatter_k<<<G_E, 256, 0, stream>>>(src, dst, cursor, srcs, E);

  // ---- init states ----
  hipMemsetAsync(hs0, 0, (size_t)N * H * 4, stream);
  hipMemsetAsync(hs1, 0, (size_t)N * H * 4, stream);
  hipMemsetAsync(zero2, 0, (size_t)N * F * 4, stream);

  auto run_gru = [&](const float* xa, int FA, float* hstate,
                     const float* W, const float* al, const float* ar, const float* b,
                     float* outp) {
    int fin = FA + H;
    if (FA == 2) {
      mm_rz_k<2><<<G_MM, 512, 0, stream>>>(xa, hstate, W, al, ar, hbuf, elrz, errz, N);
    } else {
      mm_rz_k<64><<<G_MM, 512, 0, stream>>>(xa, hstate, W, al, ar, hbuf, elrz, errz, N);
    }
    agg_rz_k<<<G_AG, 256, 0, stream>>>(rp, srcs, hbuf, elrz, errz, b, hstate, rh, zbuf, N);
    if (FA == 2) {
      mm_c_k<2><<<G_MM, 512, 0, stream>>>(xa, rh, W + (size_t)2 * fin * H, al + 128, ar + 128,
                                          hc, elc, erc, N);
    } else {
      mm_c_k<64><<<G_MM, 512, 0, stream>>>(xa, rh, W + (size_t)2 * fin * H, al + 128, ar + 128,
                                           hc, elc, erc, N);
    }
    agg_c_k<<<G_AG, 256, 0, stream>>>(rp, srcs, hc, elc, erc, b + 128, zbuf, hstate,
                                      proj_W, proj_b, outp, N);
  };

  // ---- encoder ----
  for (int t = 0; t < T; t++) {
    const float* xt = x + (size_t)t * N * F;
    run_gru(xt, 2, hs0, enc_W0, enc_al0, enc_ar0, enc_b0, nullptr);
    run_gru(hs0, 64, hs1, enc_W1, enc_al1, enc_ar1, enc_b1, nullptr);
  }

  // ---- decoder ----
  for (int t = 0; t < HZN; t++) {
    const float* xin = (t == 0) ? zero2 : (out + (size_t)(t - 1) * N * 2);
    run_gru(xin, 2, hs0, dec_W0, dec_al0, dec_ar0, dec_b0, nullptr);
    run_gru(hs0, 64, hs1, dec_W1, dec_al1, dec_ar1, dec_b1, out + (size_t)t * N * 2);
  }
  (void)out_size; (void)n_in;
}

// Round 3
// 8596.868 us; speedup vs baseline: 1.1298x; 1.0356x over previous
//
#include <hip/hip_runtime.h>
#include <hip/hip_bf16.h>

__device__ __forceinline__ float wsum64(float v) {
#pragma unroll
  for (int m = 32; m > 0; m >>= 1) v += __shfl_xor(v, m, 64);
  return v;
}
__device__ __forceinline__ float gsum16(float v) {
#pragma unroll
  for (int m = 8; m > 0; m >>= 1) v += __shfl_xor(v, m, 16);
  return v;
}
__device__ __forceinline__ float lrelu(float x) { return x > 0.f ? x : 0.2f * x; }
__device__ __forceinline__ float sigf(float x) { return 1.f / (1.f + __expf(-x)); }

// ---------------- CSR build ----------------
__global__ void hist_k(const int* __restrict__ dst, int* __restrict__ cnt, int e) {
  int i = blockIdx.x * blockDim.x + threadIdx.x;
  if (i < e) atomicAdd(&cnt[dst[i]], 1);
}

// block sums: each block (256 thr) sums 1024 counts
__global__ __launch_bounds__(256) void bsum_k(const int* __restrict__ cnt,
                                              int* __restrict__ bsum, int n) {
  __shared__ int red[4];
  int base = blockIdx.x * 1024;
  int t = threadIdx.x;
  int v = 0;
#pragma unroll
  for (int i = 0; i < 4; i++) {
    int idx = base + t + i * 256;
    v += (idx < n) ? cnt[idx] : 0;
  }
#pragma unroll
  for (int m = 32; m > 0; m >>= 1) v += __shfl_xor(v, m, 64);
  if ((t & 63) == 0) red[t >> 6] = v;
  __syncthreads();
  if (t == 0) bsum[blockIdx.x] = red[0] + red[1] + red[2] + red[3];
}

// single-block scan of <=1024 partials; bsum -> exclusive; writes grand total to rpn
__global__ __launch_bounds__(1024) void scan_bsum_k(int* __restrict__ bsum,
                                                    int* __restrict__ rpn, int nb) {
  __shared__ int buf[1024];
  int t = threadIdx.x;
  int v = (t < nb) ? bsum[t] : 0;
  buf[t] = v;
  __syncthreads();
  int val = v;
  for (int off = 1; off < 1024; off <<= 1) {
    int u = (t >= off) ? buf[t - off] : 0;
    __syncthreads();
    val += u;
    buf[t] = val;
    __syncthreads();
  }
  if (t < nb) bsum[t] = val - v;
  if (t == nb - 1) *rpn = val;
}

// per-block rescan of 1024 counts + block offset -> rp and cursor
__global__ __launch_bounds__(1024) void scan_fin_k(const int* __restrict__ cnt,
                                                   const int* __restrict__ bsum,
                                                   int* __restrict__ rp,
                                                   int* __restrict__ cursor, int n) {
  __shared__ int buf[1024];
  int t = threadIdx.x;
  int idx = blockIdx.x * 1024 + t;
  int v = (idx < n) ? cnt[idx] : 0;
  buf[t] = v;
  __syncthreads();
  int val = v;
  for (int off = 1; off < 1024; off <<= 1) {
    int u = (t >= off) ? buf[t - off] : 0;
    __syncthreads();
    val += u;
    buf[t] = val;
    __syncthreads();
  }
  if (idx < n) {
    int e = bsum[blockIdx.x] + val - v;
    rp[idx] = e;
    cursor[idx] = e;
  }
}

__global__ void scatter_k(const int* __restrict__ src, const int* __restrict__ dst,
                          int* __restrict__ cursor, int* __restrict__ srcs, int e) {
  int i = blockIdx.x * blockDim.x + threadIdx.x;
  if (i < e) {
    int pos = atomicAdd(&cursor[dst[i]], 1);
    srcs[pos] = src[i];
  }
}

// ---------------- fused dense r+z gates ----------------
template <int FA>
__global__ __launch_bounds__(512) void mm_rz_k(
    const float* __restrict__ xa, const float* __restrict__ xb,
    const float* __restrict__ Wg, const float* __restrict__ al, const float* __restrict__ ar,
    float* __restrict__ hbuf, float* __restrict__ elrz, float* __restrict__ errz, int n) {
  constexpr int FIN = FA + 64;
  __shared__ float Wl[FIN * 128];
  const float* Wr = Wg;
  const float* Wz = Wg + FIN * 64;
  for (int i = threadIdx.x; i < FIN * 64; i += 512) {
    Wl[i * 2 + 0] = Wr[i];
    Wl[i * 2 + 1] = Wz[i];
  }
  __syncthreads();
  int lane = threadIdx.x & 63, w = threadIdx.x >> 6;
  float alr = al[lane], arr_ = ar[lane];
  float alz = al[64 + lane], arz = ar[64 + lane];
  int rb = __builtin_amdgcn_readfirstlane(blockIdx.x * 64 + w * 8);
  if (rb >= n) return;
  float accr[8], accz[8];
#pragma unroll
  for (int i = 0; i < 8; i++) { accr[i] = 0.f; accz[i] = 0.f; }
  const float* pa[8];
  const float* pb[8];
#pragma unroll
  for (int i = 0; i < 8; i++) {
    int r = rb + i; if (r >= n) r = n - 1;
    pa[i] = xa + (size_t)r * FA;
    pb[i] = xb + (size_t)r * 64;
  }
#pragma unroll
  for (int k = 0; k < FA; k++) {
    float2 wv = *(const float2*)&Wl[(size_t)(k * 64 + lane) * 2];
#pragma unroll
    for (int i = 0; i < 8; i++) {
      float v = pa[i][k];
      accr[i] = fmaf(v, wv.x, accr[i]);
      accz[i] = fmaf(v, wv.y, accz[i]);
    }
  }
#pragma unroll 4
  for (int k = 0; k < 64; k++) {
    float2 wv = *(const float2*)&Wl[(size_t)((FA + k) * 64 + lane) * 2];
#pragma unroll
    for (int i = 0; i < 8; i++) {
      float v = pb[i][k];
      accr[i] = fmaf(v, wv.x, accr[i]);
      accz[i] = fmaf(v, wv.y, accz[i]);
    }
  }
#pragma unroll
  for (int i = 0; i < 8; i++) {
    int r = rb + i;
    bool ok = r < n;
    if (ok) {
      hbuf[(size_t)r * 128 + lane] = accr[i];
      hbuf[(size_t)r * 128 + 64 + lane] = accz[i];
    }
    float s;
    s = wsum64(accr[i] * alr);  if (ok && lane == 0) elrz[(size_t)r * 2 + 0] = s;
    s = wsum64(accz[i] * alz);  if (ok && lane == 0) elrz[(size_t)r * 2 + 1] = s;
    s = wsum64(accr[i] * arr_); if (ok && lane == 0) errz[(size_t)r * 2 + 0] = s;
    s = wsum64(accz[i] * arz);  if (ok && lane == 0) errz[(size_t)r * 2 + 1] = s;
  }
}

// ---------------- dense candidate gate ----------------
template <int FA>
__global__ __launch_bounds__(512) void mm_c_k(
    const float* __restrict__ xa, const float* __restrict__ xb,
    const float* __restrict__ Wc, const float* __restrict__ al, const float* __restrict__ ar,
    float* __restrict__ hc, float* __restrict__ elc, float* __restrict__ erc, int n) {
  constexpr int FIN = FA + 64;
  __shared__ float Wl[FIN * 64];
  for (int i = threadIdx.x; i < FIN * 64; i += 512) Wl[i] = Wc[i];
  __syncthreads();
  int lane = threadIdx.x & 63, w = threadIdx.x >> 6;
  float alv = al[lane], arv = ar[lane];
  int rb = __builtin_amdgcn_readfirstlane(blockIdx.x * 64 + w * 8);
  if (rb >= n) return;
  float acc[8];
#pragma unroll
  for (int i = 0; i < 8; i++) acc[i] = 0.f;
  const float* pa[8];
  const float* pb[8];
#pragma unroll
  for (int i = 0; i < 8; i++) {
    int r = rb + i; if (r >= n) r = n - 1;
    pa[i] = xa + (size_t)r * FA;
    pb[i] = xb + (size_t)r * 64;
  }
#pragma unroll
  for (int k = 0; k < FA; k++) {
    float wv = Wl[k * 64 + lane];
#pragma unroll
    for (int i = 0; i < 8; i++) acc[i] = fmaf(pa[i][k], wv, acc[i]);
  }
#pragma unroll 4
  for (int k = 0; k < 64; k++) {
    float wv = Wl[(FA + k) * 64 + lane];
#pragma unroll
    for (int i = 0; i < 8; i++) acc[i] = fmaf(pb[i][k], wv, acc[i]);
  }
#pragma unroll
  for (int i = 0; i < 8; i++) {
    int r = rb + i;
    bool ok = r < n;
    if (ok) hc[(size_t)r * 64 + lane] = acc[i];
    float s;
    s = wsum64(acc[i] * alv); if (ok && lane == 0) elc[r] = s;
    s = wsum64(acc[i] * arv); if (ok && lane == 0) erc[r] = s;
  }
}

// ---------------- edge softmax + aggregate r,z (fixed-trip unrolled gather) ----------------
__global__ __launch_bounds__(256) void agg_rz_k(
    const int* __restrict__ rp, const int* __restrict__ srcs,
    const float* __restrict__ hbuf, const float* __restrict__ elrz, const float* __restrict__ errz,
    const float* __restrict__ b,
    const float* __restrict__ hx, float* __restrict__ rh, float* __restrict__ zb, int n) {
  int l16 = threadIdx.x & 15;
  int d = (blockIdx.x * 256 + threadIdx.x) >> 4;
  if (d >= n) return;
  int beg = rp[d], deg = rp[d + 1] - beg;
  float2 erd = ((const float2*)errz)[d];
  const float4* h4 = (const float4*)hbuf;
  float4 accr = {0, 0, 0, 0}, accz = {0, 0, 0, 0};
  float sr = 0.f, sz = 0.f;
  for (int base = 0; base < deg; base += 16) {
    int k = base + l16;
    int s = 0;
    float exr = 0.f, exz = 0.f;
    if (k < deg) {
      s = srcs[beg + k];
      float2 el = ((const float2*)elrz)[s];
      exr = __expf(lrelu(el.x + erd.x));
      exz = __expf(lrelu(el.y + erd.y));
      sr += exr; sz += exz;
    }
#pragma unroll
    for (int j = 0; j < 16; j++) {
      int sj = __shfl(s, j, 16);
      float aj = __shfl(exr, j, 16);
      float zj = __shfl(exz, j, 16);
      float4 hr = h4[(size_t)sj * 32 + l16];
      float4 hz = h4[(size_t)sj * 32 + 16 + l16];
      accr.x = fmaf(aj, hr.x, accr.x); accr.y = fmaf(aj, hr.y, accr.y);
      accr.z = fmaf(aj, hr.z, accr.z); accr.w = fmaf(aj, hr.w, accr.w);
      accz.x = fmaf(zj, hz.x, accz.x); accz.y = fmaf(zj, hz.y, accz.y);
      accz.z = fmaf(zj, hz.z, accz.z); accz.w = fmaf(zj, hz.w, accz.w);
    }
  }
  sr = gsum16(sr); sz = gsum16(sz);
  float invr = 1.f / fmaxf(sr, 1e-9f);
  float invz = 1.f / fmaxf(sz, 1e-9f);
  float4 br4 = ((const float4*)b)[l16];
  float4 bz4 = ((const float4*)(b + 64))[l16];
  float4 hx4 = ((const float4*)hx)[(size_t)d * 16 + l16];
  float4 rv, zv;
  rv.x = sigf(fmaf(accr.x, invr, br4.x)) * hx4.x;
  rv.y = sigf(fmaf(accr.y, invr, br4.y)) * hx4.y;
  rv.z = sigf(fmaf(accr.z, invr, br4.z)) * hx4.z;
  rv.w = sigf(fmaf(accr.w, invr, br4.w)) * hx4.w;
  zv.x = sigf(fmaf(accz.x, invz, bz4.x));
  zv.y = sigf(fmaf(accz.y, invz, bz4.y));
  zv.z = sigf(fmaf(accz.z, invz, bz4.z));
  zv.w = sigf(fmaf(accz.w, invz, bz4.w));
  ((float4*)rh)[(size_t)d * 16 + l16] = rv;
  ((float4*)zb)[(size_t)d * 16 + l16] = zv;
}

// ---------------- candidate aggregate + state update (+ optional proj) ----------------
__global__ __launch_bounds__(256) void agg_c_k(
    const int* __restrict__ rp, const int* __restrict__ srcs,
    const float* __restrict__ hc, const float* __restrict__ elc, const float* __restrict__ erc,
    const float* __restrict__ b, const float* __restrict__ zb, float* __restrict__ hstate,
    const float* __restrict__ projW, const float* __restrict__ projb,
    float* __restrict__ outp, int n) {
  int l16 = threadIdx.x & 15;
  int d = (blockIdx.x * 256 + threadIdx.x) >> 4;
  if (d >= n) return;
  int beg = rp[d], deg = rp[d + 1] - beg;
  float erd = erc[d];
  const float4* h4 = (const float4*)hc;
  float4 acc = {0, 0, 0, 0};
  float ssum = 0.f;
  for (int base = 0; base < deg; base += 16) {
    int k = base + l16;
    int s = 0;
    float ex = 0.f;
    if (k < deg) {
      s = srcs[beg + k];
      ex = __expf(lrelu(elc[s] + erd));
      ssum += ex;
    }
#pragma unroll
    for (int j = 0; j < 16; j++) {
      int sj = __shfl(s, j, 16);
      float aj = __shfl(ex, j, 16);
      float4 hv = h4[(size_t)sj * 16 + l16];
      acc.x = fmaf(aj, hv.x, acc.x); acc.y = fmaf(aj, hv.y, acc.y);
      acc.z = fmaf(aj, hv.z, acc.z); acc.w = fmaf(aj, hv.w, acc.w);
    }
  }
  ssum = gsum16(ssum);
  float inv = 1.f / fmaxf(ssum, 1e-9f);
  float4 bc4 = ((const float4*)b)[l16];
  float4 z4 = ((const float4*)zb)[(size_t)d * 16 + l16];
  float4 hx4 = ((const float4*)hstate)[(size_t)d * 16 + l16];
  float4 hcv, hn;
  hcv.x = tanhf(fmaf(acc.x, inv, bc4.x));
  hcv.y = tanhf(fmaf(acc.y, inv, bc4.y));
  hcv.z = tanhf(fmaf(acc.z, inv, bc4.z));
  hcv.w = tanhf(fmaf(acc.w, inv, bc4.w));
  hn.x = z4.x * hx4.x + (1.f - z4.x) * hcv.x;
  hn.y = z4.y * hx4.y + (1.f - z4.y) * hcv.y;
  hn.z = z4.z * hx4.z + (1.f - z4.z) * hcv.z;
  hn.w = z4.w * hx4.w + (1.f - z4.w) * hcv.w;
  ((float4*)hstate)[(size_t)d * 16 + l16] = hn;
  if (outp) {
    const float4* wp4 = (const float4*)projW;   // [64][2] row-major
    float4 a0 = wp4[l16 * 2], a1 = wp4[l16 * 2 + 1];
    float p0 = hn.x * a0.x + hn.y * a0.z + hn.z * a1.x + hn.w * a1.z;
    float p1 = hn.x * a0.y + hn.y * a0.w + hn.z * a1.y + hn.w * a1.w;
    p0 = gsum16(p0); p1 = gsum16(p1);
    if (l16 == 0) {
      outp[(size_t)d * 2 + 0] = p0 + projb[0];
      outp[(size_t)d * 2 + 1] = p1 + projb[1];
    }
  }
}

extern "C" void kernel_launch(void* const* d_in, const int* in_sizes, int n_in,
                              void* d_out, int out_size, void* d_ws, size_t ws_size,
                              hipStream_t stream) {
  const int T = 12, HZN = 12, F = 2, H = 64;
  const float* x = (const float*)d_in[0];
  const int* src = (const int*)d_in[1];
  const int* dst = (const int*)d_in[2];
  const float* enc_W0 = (const float*)d_in[3];
  const float* enc_al0 = (const float*)d_in[4];
  const float* enc_ar0 = (const float*)d_in[5];
  const float* enc_b0 = (const float*)d_in[6];
  const float* enc_W1 = (const float*)d_in[7];
  const float* enc_al1 = (const float*)d_in[8];
  const float* enc_ar1 = (const float*)d_in[9];
  const float* enc_b1 = (const float*)d_in[10];
  const float* dec_W0 = (const float*)d_in[11];
  const float* dec_al0 = (const float*)d_in[12];
  const float* dec_ar0 = (const float*)d_in[13];
  const float* dec_b0 = (const float*)d_in[14];
  const float* dec_W1 = (const float*)d_in[15];
  const float* dec_al1 = (const float*)d_in[16];
  const float* dec_ar1 = (const float*)d_in[17];
  const float* dec_b1 = (const float*)d_in[18];
  const float* proj_W = (const float*)d_in[19];
  const float* proj_b = (const float*)d_in[20];
  float* out = (float*)d_out;

  const int E = in_sizes[1];
  const int N = in_sizes[0] / (T * F);
  const int NB = (N + 1023) / 1024;

  char* wp = (char*)d_ws;
  size_t off = 0;
  auto carve = [&](size_t bytes) {
    void* p = wp + off;
    off = (off + bytes + 255) & ~(size_t)255;
    return p;
  };
  int* counts = (int*)carve((size_t)N * 4);
  int* bsum = (int*)carve((size_t)NB * 4);
  int* rp = (int*)carve((size_t)(N + 1) * 4);
  int* cursor = (int*)carve((size_t)N * 4);
  int* srcs = (int*)carve((size_t)E * 4);
  float* hs0 = (float*)carve((size_t)N * H * 4);
  float* hs1 = (float*)carve((size_t)N * H * 4);
  float* hbuf = (float*)carve((size_t)N * 2 * H * 4);
  float* elrz = (float*)carve((size_t)N * 2 * 4);
  float* errz = (float*)carve((size_t)N * 2 * 4);
  float* hc = (float*)carve((size_t)N * H * 4);
  float* elc = (float*)carve((size_t)N * 4);
  float* erc = (float*)carve((size_t)N * 4);
  float* rh = (float*)carve((size_t)N * H * 4);
  float* zbuf = (float*)carve((size_t)N * H * 4);
  float* zero2 = (float*)carve((size_t)N * F * 4);
  (void)ws_size;

  const int G_E = (E + 255) / 256;
  const int G_MM = (N + 63) / 64;
  const int G_AG = (N + 15) / 16;

  // ---- CSR by destination ----
  hipMemsetAsync(counts, 0, (size_t)N * 4, stream);
  hist_k<<<G_E, 256, 0, stream>>>(dst, counts, E);
  bsum_k<<<NB, 256, 0, stream>>>(counts, bsum, N);
  scan_bsum_k<<<1, 1024, 0, stream>>>(bsum, rp + N, NB);
  scan_fin_k<<<NB, 1024, 0, stream>>>(counts, bsum, rp, cursor, N);
  scatter_k<<<G_E, 256, 0, stream>>>(src, dst, cursor, srcs, E);

  // ---- init states ----
  hipMemsetAsync(hs0, 0, (size_t)N * H * 4, stream);
  hipMemsetAsync(hs1, 0, (size_t)N * H * 4, stream);
  hipMemsetAsync(zero2, 0, (size_t)N * F * 4, stream);

  auto run_gru = [&](const float* xa, int FA, float* hstate,
                     const float* W, const float* al, const float* ar, const float* b,
                     float* outp) {
    int fin = FA + H;
    if (FA == 2) {
      mm_rz_k<2><<<G_MM, 512, 0, stream>>>(xa, hstate, W, al, ar, hbuf, elrz, errz, N);
    } else {
      mm_rz_k<64><<<G_MM, 512, 0, stream>>>(xa, hstate, W, al, ar, hbuf, elrz, errz, N);
    }
    agg_rz_k<<<G_AG, 256, 0, stream>>>(rp, srcs, hbuf, elrz, errz, b, hstate, rh, zbuf, N);
    if (FA == 2) {
      mm_c_k<2><<<G_MM, 512, 0, stream>>>(xa, rh, W + (size_t)2 * fin * H, al + 128, ar + 128,
                                          hc, elc, erc, N);
    } else {
      mm_c_k<64><<<G_MM, 512, 0, stream>>>(xa, rh, W + (size_t)2 * fin * H, al + 128, ar + 128,
                                           hc, elc, erc, N);
    }
    agg_c_k<<<G_AG, 256, 0, stream>>>(rp, srcs, hc, elc, erc, b + 128, zbuf, hstate,
                                      proj_W, proj_b, outp, N);
  };

  // ---- encoder ----
  for (int t = 0; t < T; t++) {
    const float* xt = x + (size_t)t * N * F;
    run_gru(xt, 2, hs0, enc_W0, enc_al0, enc_ar0, enc_b0, nullptr);
    run_gru(hs0, 64, hs1, enc_W1, enc_al1, enc_ar1, enc_b1, nullptr);
  }

  // ---- decoder ----
  for (int t = 0; t < HZN; t++) {
    const float* xin = (t == 0) ? zero2 : (out + (size_t)(t - 1) * N * 2);
    run_gru(xin, 2, hs0, dec_W0, dec_al0, dec_ar0, dec_b0, nullptr);
    run_gru(hs0, 64, hs1, dec_W1, dec_al1, dec_ar1, dec_b1, out + (size_t)t * N * 2);
  }
  (void)out_size; (void)n_in;
}